// Round 4
// baseline (91.091 us; speedup 1.0000x reference)
//
#include <hip/hip_runtime.h>
#include <math.h>

constexpr int B_ = 8, C_ = 1280, H_ = 7, W_ = 7;
constexpr int M_ = 2048, N_ = 128, HID = 256, NC = 21;
constexpr int DET_OFF = M_ * NC;          // 43008
constexpr int IOU_OFF = M_ * NC + M_ * 4; // 51200

typedef __attribute__((ext_vector_type(8))) short bf16x8;
typedef __attribute__((ext_vector_type(8))) unsigned short u16x8;
typedef __attribute__((ext_vector_type(4))) float f32x4;

// ws layout (bytes)
constexpr size_t FEATB_OFF = 0;                               // 2048*1280*2 = 5242880
constexpr size_t W1T_OFF   = 5242880;                         // 1280*256*2  =  655360
constexpr size_t W2T_OFF   = W1T_OFF + 655360;                // 256*256*2   =  131072
constexpr size_t WHT_OFF   = W2T_OFF + 131072;                // 32*256*2    =   16384

// k_aux grid partitions
constexpr int POOL_BLKS    = B_ * 20 * 2;   // img x (1280/64 ctile) x prop-half = 320
constexpr int PREP_W1_BLKS = 160;           // 1280*256 / (256*8)
constexpr int PREP_W2_BLKS = 32;            // 256*256 / (256*8)
constexpr int PREP_WH_BLKS = 4;             // 32*256 / (256*8)
constexpr int AUX_BLKS = POOL_BLKS + PREP_W1_BLKS + PREP_W2_BLKS + PREP_WH_BLKS; // 516

__device__ __forceinline__ unsigned short f2bf(float f) {
    unsigned u = __builtin_bit_cast(unsigned, f);
    u += 0x7FFFu + ((u >> 16) & 1u);   // round-to-nearest-even
    return (unsigned short)(u >> 16);
}

__device__ __forceinline__ int lowerb(const int* __restrict__ a, int n, int v) {
    int lo = 0, hi = n;
    while (lo < hi) { int mid = (lo + hi) >> 1; if (a[mid] < v) lo = mid + 1; else hi = mid; }
    return lo;
}

// ---------- fused: ROI pool (LDS-staged fmap tile) + weight prep ----------
__global__ __launch_bounds__(256) void k_aux(
    const float* __restrict__ fmap, const float* __restrict__ props,
    const int* __restrict__ pbid,
    const float* __restrict__ W1, const float* __restrict__ W2,
    const float* __restrict__ Wc, const float* __restrict__ Wd,
    unsigned short* __restrict__ featb, unsigned short* __restrict__ W1t,
    unsigned short* __restrict__ W2t,   unsigned short* __restrict__ Wht)
{
    const int tid = threadIdx.x;
    const int b = blockIdx.x;

    if (b < POOL_BLKS) {
        // ---- pool: block = (img, 64-ch tile, proposal-half) ----
        __shared__ __align__(16) float tile[64 * 49];  // 12.25 KB
        int img   = b / 40;
        int rest  = b - img * 40;
        int ctile = rest >> 1;
        int phalf = rest & 1;
        int c0    = ctile * 64;

        // stage 64x49 f32 tile: globally contiguous, float4-aligned
        const float* src = fmap + ((size_t)img * C_ + c0) * 49;
        for (int i4 = tid; i4 < 64 * 49 / 4; i4 += 256)
            *(float4*)&tile[i4 * 4] = *(const float4*)(src + i4 * 4);

        int start = lowerb(pbid, M_, img);
        int end   = lowerb(pbid, M_, img + 1);
        int cnt   = end - start;
        int half  = (cnt + 1) >> 1;
        int lo    = start + phalf * half;
        int hi    = phalf ? end : start + half;

        __syncthreads();

        int w = tid >> 6, lane = tid & 63;
        const float* tc = tile + lane * 49;   // lane = channel; 49 mod 32 coprime -> no conflicts

        for (int m = lo + w; m < hi; m += 4) {
            float4 bx = *(const float4*)(props + (size_t)m * 4);
            float x1 = rintf(bx.x), y1 = rintf(bx.y);
            float x2 = rintf(bx.z), y2 = rintf(bx.w);
            float rw = fmaxf(x2 - x1 + 1.0f, 1.0f);
            float rh = fmaxf(y2 - y1 + 1.0f, 1.0f);
            float bw = rw * 0.5f, bh = rh * 0.5f;
            int hs0 = (int)fminf(fmaxf(y1, 0.f), 7.f);
            int he0 = (int)fminf(fmaxf(ceilf(bh) + y1, 0.f), 7.f);
            int hs1 = (int)fminf(fmaxf(floorf(bh) + y1, 0.f), 7.f);
            int he1 = (int)fminf(fmaxf(ceilf(2.f * bh) + y1, 0.f), 7.f);
            int ws0 = (int)fminf(fmaxf(x1, 0.f), 7.f);
            int we0 = (int)fminf(fmaxf(ceilf(bw) + x1, 0.f), 7.f);
            int ws1 = (int)fminf(fmaxf(floorf(bw) + x1, 0.f), 7.f);
            int we1 = (int)fminf(fmaxf(ceilf(2.f * bw) + x1, 0.f), 7.f);

            float b00 = -INFINITY, b01 = -INFINITY, b10 = -INFINITY, b11 = -INFINITY;
            for (int y = hs0; y < he1; ++y) {
                float r0 = -INFINITY, r1 = -INFINITY;
                for (int x = ws0; x < we1; ++x) {
                    float v = tc[y * 7 + x];
                    if (x < we0)  r0 = fmaxf(r0, v);
                    if (x >= ws1) r1 = fmaxf(r1, v);
                }
                if (y < he0)  { b00 = fmaxf(b00, r0); b01 = fmaxf(b01, r1); }
                if (y >= hs1) { b10 = fmaxf(b10, r0); b11 = fmaxf(b11, r1); }
            }
            bool e00 = (he0 <= hs0) | (we0 <= ws0);
            bool e01 = (he0 <= hs0) | (we1 <= ws1);
            bool e10 = (he1 <= hs1) | (we0 <= ws0);
            bool e11 = (he1 <= hs1) | (we1 <= ws1);
            float s = (e00 ? 0.f : b00) + (e01 ? 0.f : b01)
                    + (e10 ? 0.f : b10) + (e11 ? 0.f : b11);
            featb[(size_t)m * C_ + c0 + lane] = f2bf(s * 0.25f);
        }
    } else if (b < POOL_BLKS + PREP_W1_BLKS) {
        // ---- W1^T: block pb handles k0 = pb*8, all 256 cols ----
        int k0 = (b - POOL_BLKS) * 8;
        int col = tid;
        u16x8 o;
        #pragma unroll
        for (int j = 0; j < 8; ++j) o[j] = f2bf(W1[(size_t)(k0 + j) * HID + col]);
        *(u16x8*)(W1t + (size_t)col * C_ + k0) = o;
    } else if (b < POOL_BLKS + PREP_W1_BLKS + PREP_W2_BLKS) {
        int k0 = (b - POOL_BLKS - PREP_W1_BLKS) * 8;
        int col = tid;
        u16x8 o;
        #pragma unroll
        for (int j = 0; j < 8; ++j) o[j] = f2bf(W2[(size_t)(k0 + j) * HID + col]);
        *(u16x8*)(W2t + (size_t)col * HID + k0) = o;
    } else {
        // ---- Whead^T (32 cols: 21 cls + 4 det + pad) ----
        int i = (b - POOL_BLKS - PREP_W1_BLKS - PREP_W2_BLKS) * 256 + tid;
        int o32 = i & 31;
        int k0  = (i >> 5) * 8;
        u16x8 o;
        #pragma unroll
        for (int j = 0; j < 8; ++j) {
            float v = 0.0f;
            if (o32 < NC) v = Wc[(size_t)(k0 + j) * NC + o32];
            else if (o32 < NC + 4) v = Wd[(size_t)(k0 + j) * 4 + (o32 - NC)];
            o[j] = f2bf(v);
        }
        *(u16x8*)(Wht + (size_t)o32 * HID + k0) = o;
    }
}

// ---------- fused FC1 -> FC2 -> heads + IoU; 8 proposals/block ----------
__global__ __launch_bounds__(256) void k_fc(
    const unsigned short* __restrict__ featb,
    const unsigned short* __restrict__ W1t,
    const unsigned short* __restrict__ W2t,
    const unsigned short* __restrict__ Wht,
    const float* __restrict__ b1v, const float* __restrict__ b2v,
    const float* __restrict__ bc,  const float* __restrict__ bd,
    const float* __restrict__ props, const int* __restrict__ pbid,
    const float* __restrict__ bbx,   const int* __restrict__ gbid,
    float* __restrict__ out)
{
    __shared__ unsigned short h1s[16][264];
    __shared__ unsigned short h2s[16][264];
    __shared__ float gbox[N_][4];
    __shared__ int   gids[N_];

    const int tid = threadIdx.x;
    const int w = tid >> 6, lane = tid & 63;
    const int r = lane & 15, g = lane >> 4;
    const int row0 = blockIdx.x * 8;          // 8 valid rows; MFMA rows 8..15 duplicate 0..7
    const int arow = row0 + (r & 7);
    const int col0 = w * 64;

    for (int i = tid; i < N_; i += 256) {
        gbox[i][0] = bbx[i * 5 + 0];
        gbox[i][1] = bbx[i * 5 + 1];
        gbox[i][2] = bbx[i * 5 + 2];
        gbox[i][3] = bbx[i * 5 + 3];
        gids[i] = gbid[i];
    }

    // ---- FC1 ----
    f32x4 acc[4];
    #pragma unroll
    for (int f = 0; f < 4; ++f) acc[f] = (f32x4){0.f, 0.f, 0.f, 0.f};

    const unsigned short* ap = featb + (size_t)arow * C_ + g * 8;
    const unsigned short* bp = W1t + (size_t)(col0 + r) * C_ + g * 8;
    for (int ks = 0; ks < C_ / 32; ++ks) {
        bf16x8 a = *(const bf16x8*)(ap + ks * 32);
        #pragma unroll
        for (int f = 0; f < 4; ++f) {
            bf16x8 b = *(const bf16x8*)(bp + (size_t)f * 16 * C_ + ks * 32);
            acc[f] = __builtin_amdgcn_mfma_f32_16x16x32_bf16(a, b, acc[f], 0, 0, 0);
        }
    }
    #pragma unroll
    for (int f = 0; f < 4; ++f) {
        int col = col0 + f * 16 + r;
        float bias = b1v[col];
        #pragma unroll
        for (int i = 0; i < 4; ++i)
            h1s[g * 4 + i][col] = f2bf(fmaxf(acc[f][i] + bias, 0.f));
    }
    __syncthreads();

    // ---- FC2 ----
    f32x4 acc2[4];
    #pragma unroll
    for (int f = 0; f < 4; ++f) acc2[f] = (f32x4){0.f, 0.f, 0.f, 0.f};

    const unsigned short* bp2 = W2t + (size_t)(col0 + r) * HID + g * 8;
    for (int ks = 0; ks < HID / 32; ++ks) {
        bf16x8 a = *(const bf16x8*)(&h1s[r][ks * 32 + g * 8]);
        #pragma unroll
        for (int f = 0; f < 4; ++f) {
            bf16x8 b = *(const bf16x8*)(bp2 + (size_t)f * 16 * HID + ks * 32);
            acc2[f] = __builtin_amdgcn_mfma_f32_16x16x32_bf16(a, b, acc2[f], 0, 0, 0);
        }
    }
    #pragma unroll
    for (int f = 0; f < 4; ++f) {
        int col = col0 + f * 16 + r;
        float bias = b2v[col];
        #pragma unroll
        for (int i = 0; i < 4; ++i)
            h2s[g * 4 + i][col] = f2bf(acc2[f][i] + bias);
    }
    __syncthreads();

    // ---- heads on wave 0: rows 0..7 valid ----
    if (w == 0) {
        f32x4 acc3[2];
        #pragma unroll
        for (int f = 0; f < 2; ++f) acc3[f] = (f32x4){0.f, 0.f, 0.f, 0.f};
        const unsigned short* bp3 = Wht + (size_t)r * HID + g * 8;
        for (int ks = 0; ks < HID / 32; ++ks) {
            bf16x8 a = *(const bf16x8*)(&h2s[r][ks * 32 + g * 8]);
            #pragma unroll
            for (int f = 0; f < 2; ++f) {
                bf16x8 b = *(const bf16x8*)(bp3 + (size_t)f * 16 * HID + ks * 32);
                acc3[f] = __builtin_amdgcn_mfma_f32_16x16x32_bf16(a, b, acc3[f], 0, 0, 0);
            }
        }
        if (g < 2) {
            #pragma unroll
            for (int f = 0; f < 2; ++f) {
                int col = f * 16 + r;
                #pragma unroll
                for (int i = 0; i < 4; ++i) {
                    int m = row0 + g * 4 + i;
                    if (col < NC)
                        out[(size_t)m * NC + col] = acc3[f][i] + bc[col];
                    else if (col < NC + 4)
                        out[DET_OFF + (size_t)m * 4 + (col - NC)] = acc3[f][i] + bd[col - NC];
                }
            }
        }
    }

    // ---- IoU: 32 threads per proposal (8 proposals) ----
    {
        int rr = tid >> 5, l = tid & 31;
        int m = row0 + rr;
        float4 bx = *(const float4*)(props + (size_t)m * 4);
        float ap2 = (bx.z - bx.x) * (bx.w - bx.y);
        int pb = pbid[m];
        float best = 0.0f;
        for (int n = l; n < N_; n += 32) {
            if (gids[n] == pb) {
                float ix = fmaxf(fminf(bx.z, gbox[n][2]) - fmaxf(bx.x, gbox[n][0]), 0.0f);
                float iy = fmaxf(fminf(bx.w, gbox[n][3]) - fmaxf(bx.y, gbox[n][1]), 0.0f);
                float inter = ix * iy;
                float ag = (gbox[n][2] - gbox[n][0]) * (gbox[n][3] - gbox[n][1]);
                float un = fmaxf(ap2 + ag - inter, 1e-6f);
                best = fmaxf(best, inter / un);
            }
        }
        #pragma unroll
        for (int off = 16; off; off >>= 1)
            best = fmaxf(best, __shfl_xor(best, off));
        if (l == 0) out[IOU_OFF + m] = best;
    }
}

extern "C" void kernel_launch(void* const* d_in, const int* in_sizes, int n_in,
                              void* d_out, int out_size, void* d_ws, size_t ws_size,
                              hipStream_t stream) {
    const float* fmap  = (const float*)d_in[0];
    const float* props = (const float*)d_in[1];
    const float* bbx   = (const float*)d_in[2];
    const float* W1    = (const float*)d_in[3];
    const float* b1v   = (const float*)d_in[4];
    const float* W2    = (const float*)d_in[5];
    const float* b2v   = (const float*)d_in[6];
    const float* Wc    = (const float*)d_in[7];
    const float* bc    = (const float*)d_in[8];
    const float* Wd    = (const float*)d_in[9];
    const float* bd    = (const float*)d_in[10];
    const int*   pbid  = (const int*)d_in[11];
    const int*   gbid  = (const int*)d_in[12];
    float* out = (float*)d_out;

    char* ws = (char*)d_ws;
    unsigned short* featb = (unsigned short*)(ws + FEATB_OFF);
    unsigned short* W1t   = (unsigned short*)(ws + W1T_OFF);
    unsigned short* W2t   = (unsigned short*)(ws + W2T_OFF);
    unsigned short* Wht   = (unsigned short*)(ws + WHT_OFF);

    k_aux<<<dim3(AUX_BLKS), dim3(256), 0, stream>>>(
        fmap, props, pbid, W1, W2, Wc, Wd, featb, W1t, W2t, Wht);
    k_fc<<<dim3(M_ / 8), dim3(256), 0, stream>>>(
        featb, W1t, W2t, Wht, b1v, b2v, bc, bd, props, pbid, bbx, gbid, out);
}